// Round 2
// baseline (1119.715 us; speedup 1.0000x reference)
//
#include <hip/hip_runtime.h>
#include <hip/hip_bf16.h>

typedef __bf16 bf16_t;
typedef __bf16 bf16x8 __attribute__((ext_vector_type(8)));
typedef __bf16 bf16x4 __attribute__((ext_vector_type(4)));
typedef float f32x4 __attribute__((ext_vector_type(4)));

#define NB 8
#define NS 4096
#define NH 256
#define NF 512
#define NE 16
#define NTOK (NB*NS)          // 32768
#define TT 64                 // tokens per tile
#define XS_STRIDE 264         // 256 + 8 pad
#define HS_STRIDE 40          // 32 + 8 pad

// ---------------------------------------------------------------------------
// Kernel 0: convert x (fp32) -> xb (bf16), straight copy
// ---------------------------------------------------------------------------
__global__ __launch_bounds__(256) void convert_x_kernel(
    const float* __restrict__ x, bf16_t* __restrict__ xb)
{
    int i = blockIdx.x * 256 + threadIdx.x;       // float4 index
    float4 v = ((const float4*)x)[i];
    bf16x4 o;
    o[0] = (bf16_t)v.x; o[1] = (bf16_t)v.y; o[2] = (bf16_t)v.z; o[3] = (bf16_t)v.w;
    ((bf16x4*)xb)[i] = o;
}

// ---------------------------------------------------------------------------
// Kernel 1: transpose+convert weights (fp32 in, bf16 out)
// w1 [E][H][F] -> w1t [E][F][H];  w2 [E][F][H] -> w2t [E][H][F]
// ---------------------------------------------------------------------------
__global__ __launch_bounds__(256) void transpose_kernel(
    const float* __restrict__ w1, const float* __restrict__ w2,
    bf16_t* __restrict__ w1t, bf16_t* __restrict__ w2t)
{
    __shared__ float tile[32][33];
    int bid = blockIdx.x;
    const float* src; bf16_t* dst; int R, C;
    if (bid < 2048) { src = w1; dst = w1t; R = NH; C = NF; }
    else            { bid -= 2048; src = w2; dst = w2t; R = NF; C = NH; }
    const int tilesPerE = 128;            // (R/32)*(C/32) = 128 both cases
    int e = bid / tilesPerE;
    int t = bid % tilesPerE;
    int tcols = C / 32;
    int tr = (t / tcols) * 32, tc = (t % tcols) * 32;
    src += (size_t)e * R * C;
    dst += (size_t)e * R * C;
    int tx = threadIdx.x & 31, ty0 = threadIdx.x >> 5;
    #pragma unroll
    for (int i = 0; i < 4; i++) {
        int ty = ty0 + i * 8;
        tile[ty][tx] = src[(size_t)(tr + ty) * C + tc + tx];
    }
    __syncthreads();
    #pragma unroll
    for (int i = 0; i < 4; i++) {
        int ty = ty0 + i * 8;
        dst[(size_t)(tc + ty) * R + tr + tx] = (bf16_t)tile[tx][ty];
    }
}

// ---------------------------------------------------------------------------
// Kernel 2: gating — fp32 logits, top-2, softmax(2), scatter to expert buckets
// one wave per token
// ---------------------------------------------------------------------------
__global__ __launch_bounds__(256) void gate_kernel(
    const float* __restrict__ x, const float* __restrict__ gate_w,
    const float* __restrict__ gate_b,
    int* __restrict__ counts, int* __restrict__ bucket_enc,
    float* __restrict__ bucket_gw)
{
    int wave = threadIdx.x >> 6;
    int lane = threadIdx.x & 63;
    int tok  = blockIdx.x * 4 + wave;
    int e = lane & 15, g = lane >> 4;
    const float* xr = x + (size_t)tok * NH;
    float acc = 0.f;
    #pragma unroll 4
    for (int i = 0; i < 64; i++) {
        int h = g * 64 + i;
        acc += xr[h] * gate_w[h * NE + e];
    }
    acc += __shfl_down(acc, 32);
    acc += __shfl_down(acc, 16);               // lanes 0..15 hold full logits
    float logit = acc + gate_b[e];

    // top-2 scan (jax.lax.top_k order: strict >, earlier index wins ties)
    float v0 = -1e30f, v1 = -1e30f; int i0 = 0, i1 = 0;
    for (int j = 0; j < 16; j++) {
        float vj = __shfl(logit, j);
        if (vj > v0)      { v1 = v0; i1 = i0; v0 = vj; i0 = j; }
        else if (vj > v1) { v1 = vj; i1 = j; }
    }
    if (lane == 0) {
        float e1 = __expf(v1 - v0);
        float s  = 1.f + e1;
        float gw0 = 1.f / s, gw1 = e1 / s;
        int p0 = atomicAdd(&counts[i0], 1);
        bucket_enc[i0 * NTOK + p0] = tok;               // k in bit 20
        bucket_gw [i0 * NTOK + p0] = gw0;
        int p1 = atomicAdd(&counts[i1], 1);
        bucket_enc[i1 * NTOK + p1] = tok | (1 << 20);
        bucket_gw [i1 * NTOK + p1] = gw1;
    }
}

// ---------------------------------------------------------------------------
// Kernel 3: fused expert FFN. Block = (expert, 64-token tile).
// GEMM1 (X@w1, K=256) -> relu -> LDS (dbuf) -> GEMM2 (H@w2, K=512 by 32)
// ---------------------------------------------------------------------------
__global__ __launch_bounds__(256, 2) void moe_kernel(
    const bf16_t* __restrict__ xb,
    const bf16_t* __restrict__ w1t,  // [E][F][H] bf16
    const float*  __restrict__ b1,   // [E][F] fp32
    const bf16_t* __restrict__ w2t,  // [E][H][F] bf16
    const float*  __restrict__ b2,   // [E][H] fp32
    const int* __restrict__ counts,
    const int* __restrict__ bucket_enc,
    const float* __restrict__ bucket_gw,
    bf16_t* __restrict__ pairbuf)    // [NTOK*2][NH] bf16
{
    __shared__ bf16_t Xs[TT][XS_STRIDE];
    __shared__ bf16_t Hs[2][TT][HS_STRIDE];
    __shared__ int   tok_s[TT];
    __shared__ float gw_s[TT];

    int e = blockIdx.y;
    int n_e = counts[e];
    int wave = threadIdx.x >> 6;
    int lane = threadIdx.x & 63;
    int l15 = lane & 15, q = lane >> 4;

    const bf16_t* w1te = w1t + (size_t)e * NF * NH;
    const bf16_t* w2te = w2t + (size_t)e * NH * NF;

    int ntiles = (n_e + TT - 1) / TT;
    for (int tile = blockIdx.x; tile < ntiles; tile += gridDim.x) {
        int tstart = tile * TT;
        __syncthreads();   // protect LDS reuse across tile iterations
        if (threadIdx.x < TT) {
            int slot = tstart + threadIdx.x;
            if (slot < n_e) {
                tok_s[threadIdx.x] = bucket_enc[e * NTOK + slot];
                gw_s [threadIdx.x] = bucket_gw [e * NTOK + slot];
            } else { tok_s[threadIdx.x] = 0; gw_s[threadIdx.x] = 0.f; }
        }
        __syncthreads();
        // stage gathered X rows: 64 rows x 512B, thread = 16B chunk
        {
            int c  = threadIdx.x & 31;
            int r0 = threadIdx.x >> 5;
            #pragma unroll
            for (int i = 0; i < 8; i++) {
                int r = r0 + i * 8;
                int tok = tok_s[r] & 0xFFFFF;
                const uint4* src = (const uint4*)(xb + (size_t)tok * NH) + c;
                *(uint4*)&Xs[r][c * 8] = *src;
            }
        }
        __syncthreads();

        f32x4 oacc[4][4];
        #pragma unroll
        for (int a = 0; a < 4; a++)
            #pragma unroll
            for (int b = 0; b < 4; b++) { f32x4 z = {0.f,0.f,0.f,0.f}; oacc[a][b] = z; }

        for (int ch = 0; ch < NF / 32; ch++) {
            int buf = ch & 1;
            // ---- GEMM1: wave's m-tile = wave; n-tiles {0,1} of this 32-col chunk
            f32x4 hacc[2]; { f32x4 z = {0.f,0.f,0.f,0.f}; hacc[0] = z; hacc[1] = z; }
            int arow = wave * 16 + l15;
            #pragma unroll
            for (int ks = 0; ks < NH / 32; ks++) {
                bf16x8 afrag = *(const bf16x8*)&Xs[arow][ks * 32 + q * 8];
                #pragma unroll
                for (int n = 0; n < 2; n++) {
                    int f = ch * 32 + n * 16 + l15;
                    bf16x8 bfrag = *(const bf16x8*)&w1te[(size_t)f * NH + ks * 32 + q * 8];
                    hacc[n] = __builtin_amdgcn_mfma_f32_16x16x32_bf16(afrag, bfrag, hacc[n], 0, 0, 0);
                }
            }
            // bias + relu -> Hs[buf] (bf16)
            #pragma unroll
            for (int n = 0; n < 2; n++) {
                int f = ch * 32 + n * 16 + l15;
                float bv = b1[e * NF + f];
                #pragma unroll
                for (int r = 0; r < 4; r++) {
                    float v = hacc[n][r] + bv;
                    v = v > 0.f ? v : 0.f;
                    Hs[buf][wave * 16 + q * 4 + r][n * 16 + l15] = (bf16_t)v;
                }
            }
            __syncthreads();
            // ---- GEMM2 partial: wave's cols [wave*64, wave*64+64), k = this chunk
            #pragma unroll
            for (int mt = 0; mt < 4; mt++) {
                bf16x8 afrag = *(const bf16x8*)&Hs[buf][mt * 16 + l15][q * 8];
                #pragma unroll
                for (int nt = 0; nt < 4; nt++) {
                    int hh = wave * 64 + nt * 16 + l15;
                    bf16x8 bfrag = *(const bf16x8*)&w2te[(size_t)hh * NF + ch * 32 + q * 8];
                    oacc[mt][nt] = __builtin_amdgcn_mfma_f32_16x16x32_bf16(afrag, bfrag, oacc[mt][nt], 0, 0, 0);
                }
            }
        }
        // ---- epilogue: +b2, *gate_weight, scatter to pair buffer
        #pragma unroll
        for (int nt = 0; nt < 4; nt++) {
            int col = wave * 64 + nt * 16 + l15;
            float b2v = b2[e * NH + col];
            #pragma unroll
            for (int mt = 0; mt < 4; mt++) {
                #pragma unroll
                for (int r = 0; r < 4; r++) {
                    int row = mt * 16 + q * 4 + r;
                    if (tstart + row < n_e) {
                        int enc = tok_s[row];
                        int tok = enc & 0xFFFFF;
                        int k   = enc >> 20;
                        float v = (oacc[mt][nt][r] + b2v) * gw_s[row];
                        pairbuf[((size_t)(tok * 2 + k)) * NH + col] = (bf16_t)v;
                    }
                }
            }
        }
    }
}

// ---------------------------------------------------------------------------
// Kernel 4: residual + LayerNorm (fp32 x, bf16 moe pair, fp32 out)
// ---------------------------------------------------------------------------
__global__ __launch_bounds__(256) void ln_kernel(
    const float* __restrict__ x, const bf16_t* __restrict__ pairbuf,
    const float* __restrict__ gamma, const float* __restrict__ beta,
    float* __restrict__ out)
{
    int tok = blockIdx.x;
    int h = threadIdx.x;
    float y = x[(size_t)tok * NH + h]
            + (float)pairbuf[(size_t)(tok * 2) * NH + h]
            + (float)pairbuf[(size_t)(tok * 2 + 1) * NH + h];
    float s = y, s2 = y * y;
    #pragma unroll
    for (int o = 32; o > 0; o >>= 1) { s += __shfl_down(s, o); s2 += __shfl_down(s2, o); }
    __shared__ float red[8];
    int wave = threadIdx.x >> 6, lane = threadIdx.x & 63;
    if (lane == 0) { red[wave] = s; red[4 + wave] = s2; }
    __syncthreads();
    if (threadIdx.x == 0) {
        float ts  = red[0] + red[1] + red[2] + red[3];
        float ts2 = red[4] + red[5] + red[6] + red[7];
        float mu  = ts / NH;
        float var = ts2 / NH - mu * mu;
        red[0] = mu;
        red[1] = rsqrtf(var + 1e-5f);
    }
    __syncthreads();
    float mu = red[0], rstd = red[1];
    out[(size_t)tok * NH + h] = ((y - mu) * rstd) * gamma[h] + beta[h];
}

// ---------------------------------------------------------------------------
extern "C" void kernel_launch(void* const* d_in, const int* in_sizes, int n_in,
                              void* d_out, int out_size, void* d_ws, size_t ws_size,
                              hipStream_t stream) {
    const float* x      = (const float*)d_in[0];
    const float* gate_w = (const float*)d_in[1];
    const float* gate_b = (const float*)d_in[2];
    const float* w1     = (const float*)d_in[3];
    const float* b1     = (const float*)d_in[4];
    const float* w2     = (const float*)d_in[5];
    const float* b2     = (const float*)d_in[6];
    const float* gamma  = (const float*)d_in[7];
    const float* beta   = (const float*)d_in[8];
    float* out = (float*)d_out;

    char* ws = (char*)d_ws;
    const size_t MB = 1024 * 1024;
    int*    counts     = (int*)ws;                       // 256 B
    int*    bucket_enc = (int*)(ws + 256);               // 2 MB
    float*  bucket_gw  = (float*)(ws + 256 + 2 * MB);    // 2 MB
    bf16_t* w1t        = (bf16_t*)(ws + 256 + 4 * MB);   // 4 MB
    bf16_t* w2t        = (bf16_t*)(ws + 256 + 8 * MB);   // 4 MB
    bf16_t* xb         = (bf16_t*)(ws + 256 + 12 * MB);  // 16 MB
    bf16_t* pairbuf    = (bf16_t*)(ws + 256 + 28 * MB);  // 32 MB

    hipMemsetAsync(counts, 0, 256, stream);
    convert_x_kernel<<<(NTOK * NH / 4) / 256, 256, 0, stream>>>(x, xb);
    transpose_kernel<<<4096, 256, 0, stream>>>(w1, w2, w1t, w2t);
    gate_kernel<<<NTOK / 4, 256, 0, stream>>>(x, gate_w, gate_b, counts, bucket_enc, bucket_gw);
    moe_kernel<<<dim3(64, NE), 256, 0, stream>>>(xb, w1t, b1, w2t, b2, counts, bucket_enc, bucket_gw, pairbuf);
    ln_kernel<<<NTOK, 256, 0, stream>>>(x, pairbuf, gamma, beta, out);
}

// Round 3
// 406.404 us; speedup vs baseline: 2.7552x; 2.7552x over previous
//
#include <hip/hip_runtime.h>
#include <hip/hip_bf16.h>

typedef __bf16 bf16_t;
typedef __bf16 bf16x8 __attribute__((ext_vector_type(8)));
typedef __bf16 bf16x4 __attribute__((ext_vector_type(4)));
typedef float f32x4 __attribute__((ext_vector_type(4)));

#define NB 8
#define NS 4096
#define NH 256
#define NF 512
#define NE 16
#define NTOK (NB*NS)          // 32768
#define TT 64                 // tokens per tile
#define XS_STRIDE 264         // 256 + 8 pad
#define HS_STRIDE 40          // 32 + 8 pad

// ---------------------------------------------------------------------------
// Kernel 0: convert x (fp32) -> xb (bf16), straight copy
// ---------------------------------------------------------------------------
__global__ __launch_bounds__(256) void convert_x_kernel(
    const float* __restrict__ x, bf16_t* __restrict__ xb)
{
    int i = blockIdx.x * 256 + threadIdx.x;       // float4 index
    float4 v = ((const float4*)x)[i];
    bf16x4 o;
    o[0] = (bf16_t)v.x; o[1] = (bf16_t)v.y; o[2] = (bf16_t)v.z; o[3] = (bf16_t)v.w;
    ((bf16x4*)xb)[i] = o;
}

// ---------------------------------------------------------------------------
// Kernel 1: transpose+convert weights (fp32 in, bf16 out)
// w1 [E][H][F] -> w1t [E][F][H];  w2 [E][F][H] -> w2t [E][H][F]
// ---------------------------------------------------------------------------
__global__ __launch_bounds__(256) void transpose_kernel(
    const float* __restrict__ w1, const float* __restrict__ w2,
    bf16_t* __restrict__ w1t, bf16_t* __restrict__ w2t)
{
    __shared__ float tile[32][33];
    int bid = blockIdx.x;
    const float* src; bf16_t* dst; int R, C;
    if (bid < 2048) { src = w1; dst = w1t; R = NH; C = NF; }
    else            { bid -= 2048; src = w2; dst = w2t; R = NF; C = NH; }
    const int tilesPerE = 128;            // (R/32)*(C/32) = 128 both cases
    int e = bid / tilesPerE;
    int t = bid % tilesPerE;
    int tcols = C / 32;
    int tr = (t / tcols) * 32, tc = (t % tcols) * 32;
    src += (size_t)e * R * C;
    dst += (size_t)e * R * C;
    int tx = threadIdx.x & 31, ty0 = threadIdx.x >> 5;
    #pragma unroll
    for (int i = 0; i < 4; i++) {
        int ty = ty0 + i * 8;
        tile[ty][tx] = src[(size_t)(tr + ty) * C + tc + tx];
    }
    __syncthreads();
    #pragma unroll
    for (int i = 0; i < 4; i++) {
        int ty = ty0 + i * 8;
        dst[(size_t)(tc + ty) * R + tr + tx] = (bf16_t)tile[tx][ty];
    }
}

// ---------------------------------------------------------------------------
// Kernel 2: gating — thread-per-token logits, top-2, softmax(2), hierarchical
// bucket scatter: LDS histogram -> 1 global atomic per (block, expert).
// 64 blocks x 512 tokens: global atomic chain = 64/address (~12us) vs 4096
// (758us measured in round 2).
// ---------------------------------------------------------------------------
__global__ __launch_bounds__(256) void gate_kernel(
    const float* __restrict__ x, const float* __restrict__ gate_w,
    const float* __restrict__ gate_b,
    int* __restrict__ counts, int* __restrict__ bucket_enc,
    float* __restrict__ bucket_gw)
{
    __shared__ float gws[NH][NE];   // 16 KB
    __shared__ int lcnt[NE];
    __shared__ int gbase[NE];

    for (int i = threadIdx.x; i < NH * NE; i += 256)
        gws[i >> 4][i & 15] = gate_w[i];
    if (threadIdx.x < NE) lcnt[threadIdx.x] = 0;
    __syncthreads();

    int   pe[2][2];   // [token][k] expert id
    int   po[2][2];   // local offset in block-histogram
    float pg[2][2];   // gate weight
    int   toks[2];

    #pragma unroll
    for (int t = 0; t < 2; t++) {
        int tok = blockIdx.x * 512 + t * 256 + threadIdx.x;
        toks[t] = tok;
        const float4* xr = (const float4*)(x + (size_t)tok * NH);
        float acc[NE];
        #pragma unroll
        for (int e = 0; e < NE; e++) acc[e] = gate_b[e];
        for (int h4 = 0; h4 < NH / 4; h4++) {
            float4 xv = xr[h4];
            #pragma unroll
            for (int j = 0; j < 4; j++) {
                float xs = (j == 0) ? xv.x : (j == 1) ? xv.y : (j == 2) ? xv.z : xv.w;
                int h = h4 * 4 + j;
                #pragma unroll
                for (int e = 0; e < NE; e++) acc[e] += xs * gws[h][e];
            }
        }
        // top-2 (jax.lax.top_k: strict >, earlier index wins ties)
        float v0 = -1e30f, v1 = -1e30f; int i0 = 0, i1 = 0;
        #pragma unroll
        for (int e = 0; e < NE; e++) {
            float a = acc[e];
            if (a > v0)      { v1 = v0; i1 = i0; v0 = a; i0 = e; }
            else if (a > v1) { v1 = a; i1 = e; }
        }
        float e1 = __expf(v1 - v0);
        float s  = 1.f + e1;
        pe[t][0] = i0; pe[t][1] = i1;
        pg[t][0] = 1.f / s; pg[t][1] = e1 / s;
        po[t][0] = atomicAdd(&lcnt[i0], 1);
        po[t][1] = atomicAdd(&lcnt[i1], 1);
    }
    __syncthreads();
    if (threadIdx.x < NE)
        gbase[threadIdx.x] = atomicAdd(&counts[threadIdx.x], lcnt[threadIdx.x]);
    __syncthreads();
    #pragma unroll
    for (int t = 0; t < 2; t++)
        #pragma unroll
        for (int k = 0; k < 2; k++) {
            int e = pe[t][k];
            int pos = gbase[e] + po[t][k];
            bucket_enc[e * NTOK + pos] = toks[t] | (k << 20);
            bucket_gw [e * NTOK + pos] = pg[t][k];
        }
}

// ---------------------------------------------------------------------------
// Kernel 3: fused expert FFN. Block = (expert, 64-token tile).
// GEMM1 (X@w1, K=256) -> relu -> LDS (dbuf) -> GEMM2 (H@w2, K=512 by 32)
// ---------------------------------------------------------------------------
__global__ __launch_bounds__(256, 2) void moe_kernel(
    const bf16_t* __restrict__ xb,
    const bf16_t* __restrict__ w1t,  // [E][F][H] bf16
    const float*  __restrict__ b1,   // [E][F] fp32
    const bf16_t* __restrict__ w2t,  // [E][H][F] bf16
    const float*  __restrict__ b2,   // [E][H] fp32
    const int* __restrict__ counts,
    const int* __restrict__ bucket_enc,
    const float* __restrict__ bucket_gw,
    bf16_t* __restrict__ pairbuf)    // [NTOK*2][NH] bf16
{
    __shared__ bf16_t Xs[TT][XS_STRIDE];
    __shared__ bf16_t Hs[2][TT][HS_STRIDE];
    __shared__ int   tok_s[TT];
    __shared__ float gw_s[TT];

    int e = blockIdx.y;
    int n_e = counts[e];
    int wave = threadIdx.x >> 6;
    int lane = threadIdx.x & 63;
    int l15 = lane & 15, q = lane >> 4;

    const bf16_t* w1te = w1t + (size_t)e * NF * NH;
    const bf16_t* w2te = w2t + (size_t)e * NH * NF;

    int ntiles = (n_e + TT - 1) / TT;
    for (int tile = blockIdx.x; tile < ntiles; tile += gridDim.x) {
        int tstart = tile * TT;
        __syncthreads();   // protect LDS reuse across tile iterations
        if (threadIdx.x < TT) {
            int slot = tstart + threadIdx.x;
            if (slot < n_e) {
                tok_s[threadIdx.x] = bucket_enc[e * NTOK + slot];
                gw_s [threadIdx.x] = bucket_gw [e * NTOK + slot];
            } else { tok_s[threadIdx.x] = 0; gw_s[threadIdx.x] = 0.f; }
        }
        __syncthreads();
        // stage gathered X rows: 64 rows x 512B, thread = 16B chunk
        {
            int c  = threadIdx.x & 31;
            int r0 = threadIdx.x >> 5;
            #pragma unroll
            for (int i = 0; i < 8; i++) {
                int r = r0 + i * 8;
                int tok = tok_s[r] & 0xFFFFF;
                const uint4* src = (const uint4*)(xb + (size_t)tok * NH) + c;
                *(uint4*)&Xs[r][c * 8] = *src;
            }
        }
        __syncthreads();

        f32x4 oacc[4][4];
        #pragma unroll
        for (int a = 0; a < 4; a++)
            #pragma unroll
            for (int b = 0; b < 4; b++) { f32x4 z = {0.f,0.f,0.f,0.f}; oacc[a][b] = z; }

        for (int ch = 0; ch < NF / 32; ch++) {
            int buf = ch & 1;
            // ---- GEMM1: wave's m-tile = wave; n-tiles {0,1} of this 32-col chunk
            f32x4 hacc[2]; { f32x4 z = {0.f,0.f,0.f,0.f}; hacc[0] = z; hacc[1] = z; }
            int arow = wave * 16 + l15;
            #pragma unroll
            for (int ks = 0; ks < NH / 32; ks++) {
                bf16x8 afrag = *(const bf16x8*)&Xs[arow][ks * 32 + q * 8];
                #pragma unroll
                for (int n = 0; n < 2; n++) {
                    int f = ch * 32 + n * 16 + l15;
                    bf16x8 bfrag = *(const bf16x8*)&w1te[(size_t)f * NH + ks * 32 + q * 8];
                    hacc[n] = __builtin_amdgcn_mfma_f32_16x16x32_bf16(afrag, bfrag, hacc[n], 0, 0, 0);
                }
            }
            // bias + relu -> Hs[buf] (bf16)
            #pragma unroll
            for (int n = 0; n < 2; n++) {
                int f = ch * 32 + n * 16 + l15;
                float bv = b1[e * NF + f];
                #pragma unroll
                for (int r = 0; r < 4; r++) {
                    float v = hacc[n][r] + bv;
                    v = v > 0.f ? v : 0.f;
                    Hs[buf][wave * 16 + q * 4 + r][n * 16 + l15] = (bf16_t)v;
                }
            }
            __syncthreads();
            // ---- GEMM2 partial: wave's cols [wave*64, wave*64+64), k = this chunk
            #pragma unroll
            for (int mt = 0; mt < 4; mt++) {
                bf16x8 afrag = *(const bf16x8*)&Hs[buf][mt * 16 + l15][q * 8];
                #pragma unroll
                for (int nt = 0; nt < 4; nt++) {
                    int hh = wave * 64 + nt * 16 + l15;
                    bf16x8 bfrag = *(const bf16x8*)&w2te[(size_t)hh * NF + ch * 32 + q * 8];
                    oacc[mt][nt] = __builtin_amdgcn_mfma_f32_16x16x32_bf16(afrag, bfrag, oacc[mt][nt], 0, 0, 0);
                }
            }
        }
        // ---- epilogue: +b2, *gate_weight, scatter to pair buffer
        #pragma unroll
        for (int nt = 0; nt < 4; nt++) {
            int col = wave * 64 + nt * 16 + l15;
            float b2v = b2[e * NH + col];
            #pragma unroll
            for (int mt = 0; mt < 4; mt++) {
                #pragma unroll
                for (int r = 0; r < 4; r++) {
                    int row = mt * 16 + q * 4 + r;
                    if (tstart + row < n_e) {
                        int enc = tok_s[row];
                        int tok = enc & 0xFFFFF;
                        int k   = enc >> 20;
                        float v = (oacc[mt][nt][r] + b2v) * gw_s[row];
                        pairbuf[((size_t)(tok * 2 + k)) * NH + col] = (bf16_t)v;
                    }
                }
            }
        }
    }
}

// ---------------------------------------------------------------------------
// Kernel 4: residual + LayerNorm (fp32 x, bf16 moe pair, fp32 out)
// ---------------------------------------------------------------------------
__global__ __launch_bounds__(256) void ln_kernel(
    const float* __restrict__ x, const bf16_t* __restrict__ pairbuf,
    const float* __restrict__ gamma, const float* __restrict__ beta,
    float* __restrict__ out)
{
    int tok = blockIdx.x;
    int h = threadIdx.x;
    float y = x[(size_t)tok * NH + h]
            + (float)pairbuf[(size_t)(tok * 2) * NH + h]
            + (float)pairbuf[(size_t)(tok * 2 + 1) * NH + h];
    float s = y, s2 = y * y;
    #pragma unroll
    for (int o = 32; o > 0; o >>= 1) { s += __shfl_down(s, o); s2 += __shfl_down(s2, o); }
    __shared__ float red[8];
    int wave = threadIdx.x >> 6, lane = threadIdx.x & 63;
    if (lane == 0) { red[wave] = s; red[4 + wave] = s2; }
    __syncthreads();
    if (threadIdx.x == 0) {
        float ts  = red[0] + red[1] + red[2] + red[3];
        float ts2 = red[4] + red[5] + red[6] + red[7];
        float mu  = ts / NH;
        float var = ts2 / NH - mu * mu;
        red[0] = mu;
        red[1] = rsqrtf(var + 1e-5f);
    }
    __syncthreads();
    float mu = red[0], rstd = red[1];
    out[(size_t)tok * NH + h] = ((y - mu) * rstd) * gamma[h] + beta[h];
}

// ---------------------------------------------------------------------------
extern "C" void kernel_launch(void* const* d_in, const int* in_sizes, int n_in,
                              void* d_out, int out_size, void* d_ws, size_t ws_size,
                              hipStream_t stream) {
    const float* x      = (const float*)d_in[0];
    const float* gate_w = (const float*)d_in[1];
    const float* gate_b = (const float*)d_in[2];
    const float* w1     = (const float*)d_in[3];
    const float* b1     = (const float*)d_in[4];
    const float* w2     = (const float*)d_in[5];
    const float* b2     = (const float*)d_in[6];
    const float* gamma  = (const float*)d_in[7];
    const float* beta   = (const float*)d_in[8];
    float* out = (float*)d_out;

    char* ws = (char*)d_ws;
    const size_t MB = 1024 * 1024;
    int*    counts     = (int*)ws;                       // 256 B
    int*    bucket_enc = (int*)(ws + 256);               // 2 MB
    float*  bucket_gw  = (float*)(ws + 256 + 2 * MB);    // 2 MB
    bf16_t* w1t        = (bf16_t*)(ws + 256 + 4 * MB);   // 4 MB
    bf16_t* w2t        = (bf16_t*)(ws + 256 + 8 * MB);   // 4 MB
    bf16_t* xb         = (bf16_t*)(ws + 256 + 12 * MB);  // 16 MB
    bf16_t* pairbuf    = (bf16_t*)(ws + 256 + 28 * MB);  // 32 MB

    hipMemsetAsync(counts, 0, 256, stream);
    convert_x_kernel<<<(NTOK * NH / 4) / 256, 256, 0, stream>>>(x, xb);
    transpose_kernel<<<4096, 256, 0, stream>>>(w1, w2, w1t, w2t);
    gate_kernel<<<64, 256, 0, stream>>>(x, gate_w, gate_b, counts, bucket_enc, bucket_gw);
    moe_kernel<<<dim3(64, NE), 256, 0, stream>>>(xb, w1t, b1, w2t, b2, counts, bucket_enc, bucket_gw, pairbuf);
    ln_kernel<<<NTOK, 256, 0, stream>>>(x, pairbuf, gamma, beta, out);
}

// Round 4
// 278.949 us; speedup vs baseline: 4.0141x; 1.4569x over previous
//
#include <hip/hip_runtime.h>
#include <hip/hip_bf16.h>

typedef __bf16 bf16_t;
typedef __bf16 bf16x8 __attribute__((ext_vector_type(8)));
typedef __bf16 bf16x4 __attribute__((ext_vector_type(4)));
typedef float f32x4 __attribute__((ext_vector_type(4)));

#define NB 8
#define NS 4096
#define NH 256
#define NF 512
#define NE 16
#define NTOK (NB*NS)          // 32768
#define TT 64                 // tokens per tile
#define NCH 16                // f-chunks of 32
#define XS_STRIDE 264         // 256 + 8 pad (528B = 33*16: aligned rows, conflict-free)
#define HS_STRIDE 40          // 32 + 8 pad (80B = 5*16)

// ---------------------------------------------------------------------------
// Kernel 1: transpose+convert weights (fp32 in, bf16 out)
// w1 [E][H][F] -> w1t [E][F][H]  with XOR bank-swizzle baked into the k index:
//   element (f,k) stored at f*256 + ((k>>3)^(f&7))*8 + (k&7)
// w2 [E][F][H] -> w2t [E][H][F]  linear
// ---------------------------------------------------------------------------
__global__ __launch_bounds__(256) void transpose_kernel(
    const float* __restrict__ w1, const float* __restrict__ w2,
    bf16_t* __restrict__ w1t, bf16_t* __restrict__ w2t)
{
    __shared__ float tile[32][33];
    int bid = blockIdx.x;
    const float* src; bf16_t* dst; int R, C; int isw1;
    if (bid < 2048) { src = w1; dst = w1t; R = NH; C = NF; isw1 = 1; }
    else            { bid -= 2048; src = w2; dst = w2t; R = NF; C = NH; isw1 = 0; }
    const int tilesPerE = 128;
    int e = bid / tilesPerE;
    int t = bid % tilesPerE;
    int tcols = C / 32;
    int tr = (t / tcols) * 32, tc = (t % tcols) * 32;
    src += (size_t)e * R * C;
    dst += (size_t)e * R * C;
    int tx = threadIdx.x & 31, ty0 = threadIdx.x >> 5;
    #pragma unroll
    for (int i = 0; i < 4; i++) {
        int ty = ty0 + i * 8;
        tile[ty][tx] = src[(size_t)(tr + ty) * C + tc + tx];
    }
    __syncthreads();
    #pragma unroll
    for (int i = 0; i < 4; i++) {
        int ty = ty0 + i * 8;
        int drow = tc + ty;          // f for w1, h for w2
        int dcol = tr + tx;          // k(=h) for w1, f for w2
        size_t idx;
        if (isw1) {
            int swz = (((dcol >> 3) ^ (drow & 7)) << 3) | (dcol & 7);
            idx = (size_t)drow * NH + swz;
        } else {
            idx = (size_t)drow * R + dcol;
        }
        dst[idx] = (bf16_t)tile[tx][ty];
    }
}

// ---------------------------------------------------------------------------
// Kernel 2: gating (fp32 logits, top-2, softmax(2), hierarchical scatter)
// + fused x fp32->bf16 conversion (we already read every x row here)
// ---------------------------------------------------------------------------
__global__ __launch_bounds__(256) void gate_kernel(
    const float* __restrict__ x, const float* __restrict__ gate_w,
    const float* __restrict__ gate_b,
    int* __restrict__ counts, int* __restrict__ bucket_enc,
    float* __restrict__ bucket_gw, bf16_t* __restrict__ xb)
{
    __shared__ float gws[NH][NE];   // 16 KB
    __shared__ int lcnt[NE];
    __shared__ int gbase[NE];

    for (int i = threadIdx.x; i < NH * NE; i += 256)
        gws[i >> 4][i & 15] = gate_w[i];
    if (threadIdx.x < NE) lcnt[threadIdx.x] = 0;
    __syncthreads();

    int   pe[2][2];
    int   po[2][2];
    float pg[2][2];
    int   toks[2];

    #pragma unroll
    for (int t = 0; t < 2; t++) {
        int tok = blockIdx.x * 512 + t * 256 + threadIdx.x;
        toks[t] = tok;
        const float4* xr = (const float4*)(x + (size_t)tok * NH);
        bf16x4* xbr = (bf16x4*)(xb + (size_t)tok * NH);
        float acc[NE];
        #pragma unroll
        for (int e = 0; e < NE; e++) acc[e] = gate_b[e];
        for (int h4 = 0; h4 < NH / 4; h4++) {
            float4 xv = xr[h4];
            bf16x4 xo;
            xo[0] = (bf16_t)xv.x; xo[1] = (bf16_t)xv.y;
            xo[2] = (bf16_t)xv.z; xo[3] = (bf16_t)xv.w;
            xbr[h4] = xo;
            #pragma unroll
            for (int j = 0; j < 4; j++) {
                float xs = (j == 0) ? xv.x : (j == 1) ? xv.y : (j == 2) ? xv.z : xv.w;
                int h = h4 * 4 + j;
                #pragma unroll
                for (int e = 0; e < NE; e++) acc[e] += xs * gws[h][e];
            }
        }
        // top-2 (jax.lax.top_k order: strict >, earlier index wins ties)
        float v0 = -1e30f, v1 = -1e30f; int i0 = 0, i1 = 0;
        #pragma unroll
        for (int e = 0; e < NE; e++) {
            float a = acc[e];
            if (a > v0)      { v1 = v0; i1 = i0; v0 = a; i0 = e; }
            else if (a > v1) { v1 = a; i1 = e; }
        }
        float e1 = __expf(v1 - v0);
        float s  = 1.f + e1;
        pe[t][0] = i0; pe[t][1] = i1;
        pg[t][0] = 1.f / s; pg[t][1] = e1 / s;
        po[t][0] = atomicAdd(&lcnt[i0], 1);
        po[t][1] = atomicAdd(&lcnt[i1], 1);
    }
    __syncthreads();
    if (threadIdx.x < NE)
        gbase[threadIdx.x] = atomicAdd(&counts[threadIdx.x], lcnt[threadIdx.x]);
    __syncthreads();
    #pragma unroll
    for (int t = 0; t < 2; t++)
        #pragma unroll
        for (int k = 0; k < 2; k++) {
            int e = pe[t][k];
            int pos = gbase[e] + po[t][k];
            bucket_enc[e * NTOK + pos] = toks[t] | (k << 20);
            bucket_gw [e * NTOK + pos] = pg[t][k];
        }
}

// ---------------------------------------------------------------------------
// Kernel 3: fused expert FFN, v3.
// Block = (expert via XCD-swizzle, 64-token tile). w1 chunk staged in LDS
// (double-buffered, prefetched); w2 frags hoisted global loads (L2-resident
// thanks to 2-experts-per-XCD block swizzle); 1 sync per chunk.
// ---------------------------------------------------------------------------
__global__ __launch_bounds__(256, 2) void moe_kernel(
    const bf16_t* __restrict__ xb,
    const bf16_t* __restrict__ w1t,  // [E][F][H] bf16, k-swizzled
    const float*  __restrict__ b1,
    const bf16_t* __restrict__ w2t,  // [E][H][F] bf16, linear
    const float*  __restrict__ b2,
    const int* __restrict__ counts,
    const int* __restrict__ bucket_enc,
    const float* __restrict__ bucket_gw,
    bf16_t* __restrict__ pairbuf)    // [NTOK*2][NH] bf16
{
    __shared__ __align__(16) bf16_t Xs[TT][XS_STRIDE];      // 33792 B
    __shared__ uint4 W1s4[2][1024];                          // 32768 B (2x16KB)
    __shared__ __align__(16) bf16_t Hs[2][TT][HS_STRIDE];    // 10240 B
    __shared__ int   tok_s[TT];
    __shared__ float gw_s[TT];

    int flat = blockIdx.x;
    // XCD-locality swizzle: xcd = flat % 8 (dispatch heuristic); 2 experts/XCD
    int e     = (flat & 7) * 2 + ((flat >> 3) & 1);
    int tile0 = flat >> 4;                 // 0..63
    int n_e = counts[e];
    int wave = threadIdx.x >> 6;
    int lane = threadIdx.x & 63;
    int l15 = lane & 15, q = lane >> 4;

    const bf16_t* w1te = w1t + (size_t)e * NF * NH;
    const bf16_t* w2te = w2t + (size_t)e * NH * NF;

    int ntiles = (n_e + TT - 1) / TT;
    for (int tile = tile0; tile < ntiles; tile += 64) {
        int tstart = tile * TT;
        __syncthreads();   // protect LDS reuse across tile iterations
        if (threadIdx.x < TT) {
            int slot = tstart + threadIdx.x;
            if (slot < n_e) {
                tok_s[threadIdx.x] = bucket_enc[e * NTOK + slot];
                gw_s [threadIdx.x] = bucket_gw [e * NTOK + slot];
            } else { tok_s[threadIdx.x] = 0; gw_s[threadIdx.x] = 0.f; }
        }
        __syncthreads();
        // stage gathered X rows (64 x 512B) + w1 chunk 0 (16KB)
        {
            int c  = threadIdx.x & 31;
            int r0 = threadIdx.x >> 5;
            #pragma unroll
            for (int i = 0; i < 8; i++) {
                int r = r0 + i * 8;
                int tok = tok_s[r] & 0xFFFFF;
                const uint4* src = (const uint4*)(xb + (size_t)tok * NH) + c;
                *(uint4*)&Xs[r][c * 8] = *src;
            }
            const uint4* gw1 = (const uint4*)w1te;   // chunk 0
            #pragma unroll
            for (int i = 0; i < 4; i++)
                W1s4[0][i * 256 + threadIdx.x] = gw1[i * 256 + threadIdx.x];
        }
        __syncthreads();

        f32x4 oacc[4][4];
        #pragma unroll
        for (int a = 0; a < 4; a++)
            #pragma unroll
            for (int b = 0; b < 4; b++) { f32x4 z = {0.f,0.f,0.f,0.f}; oacc[a][b] = z; }

        for (int ch = 0; ch < NCH; ch++) {
            int buf = ch & 1;
            // -- prefetch w1 chunk ch+1 into registers (lands in W1s[buf^1])
            uint4 pf[4];
            bool do_pf = (ch + 1 < NCH);
            if (do_pf) {
                const uint4* gw1 = (const uint4*)(w1te + (size_t)(ch + 1) * 32 * NH);
                #pragma unroll
                for (int i = 0; i < 4; i++) pf[i] = gw1[i * 256 + threadIdx.x];
            }
            // -- hoisted w2 B-fragments for this chunk (reuse x4 in GEMM2)
            bf16x8 bf2[4];
            #pragma unroll
            for (int nt = 0; nt < 4; nt++) {
                int hh = wave * 64 + nt * 16 + l15;
                bf2[nt] = *(const bf16x8*)&w2te[(size_t)hh * NF + ch * 32 + q * 8];
            }
            // ---- GEMM1: m-tile = wave, n-tiles {0,1}, K=256, B from LDS
            f32x4 hacc[2]; { f32x4 z = {0.f,0.f,0.f,0.f}; hacc[0] = z; hacc[1] = z; }
            const bf16_t* w1s = (const bf16_t*)W1s4[buf];
            #pragma unroll
            for (int ks = 0; ks < NH / 32; ks++) {
                bf16x8 afrag = *(const bf16x8*)&Xs[wave * 16 + l15][ks * 32 + q * 8];
                #pragma unroll
                for (int n = 0; n < 2; n++) {
                    int fl = n * 16 + l15;
                    bf16x8 bfrag = *(const bf16x8*)&w1s[fl * NH + ((((ks * 4 + q) ^ (fl & 7))) << 3)];
                    hacc[n] = __builtin_amdgcn_mfma_f32_16x16x32_bf16(afrag, bfrag, hacc[n], 0, 0, 0);
                }
            }
            // bias + relu -> Hs[buf]
            #pragma unroll
            for (int n = 0; n < 2; n++) {
                int f = ch * 32 + n * 16 + l15;
                float bv = b1[e * NF + f];
                #pragma unroll
                for (int r = 0; r < 4; r++) {
                    float v = hacc[n][r] + bv;
                    v = v > 0.f ? v : 0.f;
                    Hs[buf][wave * 16 + q * 4 + r][n * 16 + l15] = (bf16_t)v;
                }
            }
            // -- commit w1 prefetch to LDS (buffer last read before prev sync)
            if (do_pf) {
                #pragma unroll
                for (int i = 0; i < 4; i++)
                    W1s4[buf ^ 1][i * 256 + threadIdx.x] = pf[i];
            }
            __syncthreads();
            // ---- GEMM2 partial: wave's 64 out-cols, k = this 32-f chunk
            #pragma unroll
            for (int mt = 0; mt < 4; mt++) {
                bf16x8 afrag = *(const bf16x8*)&Hs[buf][mt * 16 + l15][q * 8];
                #pragma unroll
                for (int nt = 0; nt < 4; nt++) {
                    oacc[mt][nt] = __builtin_amdgcn_mfma_f32_16x16x32_bf16(afrag, bf2[nt], oacc[mt][nt], 0, 0, 0);
                }
            }
        }
        // ---- epilogue: +b2, *gate_weight, scatter to pair buffer
        #pragma unroll
        for (int nt = 0; nt < 4; nt++) {
            int col = wave * 64 + nt * 16 + l15;
            float b2v = b2[e * NH + col];
            #pragma unroll
            for (int mt = 0; mt < 4; mt++) {
                #pragma unroll
                for (int r = 0; r < 4; r++) {
                    int row = mt * 16 + q * 4 + r;
                    if (tstart + row < n_e) {
                        int enc = tok_s[row];
                        int tok = enc & 0xFFFFF;
                        int k   = enc >> 20;
                        float v = (oacc[mt][nt][r] + b2v) * gw_s[row];
                        pairbuf[((size_t)(tok * 2 + k)) * NH + col] = (bf16_t)v;
                    }
                }
            }
        }
    }
}

// ---------------------------------------------------------------------------
// Kernel 4: residual + LayerNorm (fp32 x, bf16 moe pair, fp32 out)
// ---------------------------------------------------------------------------
__global__ __launch_bounds__(256) void ln_kernel(
    const float* __restrict__ x, const bf16_t* __restrict__ pairbuf,
    const float* __restrict__ gamma, const float* __restrict__ beta,
    float* __restrict__ out)
{
    int tok = blockIdx.x;
    int h = threadIdx.x;
    float y = x[(size_t)tok * NH + h]
            + (float)pairbuf[(size_t)(tok * 2) * NH + h]
            + (float)pairbuf[(size_t)(tok * 2 + 1) * NH + h];
    float s = y, s2 = y * y;
    #pragma unroll
    for (int o = 32; o > 0; o >>= 1) { s += __shfl_down(s, o); s2 += __shfl_down(s2, o); }
    __shared__ float red[8];
    int wave = threadIdx.x >> 6, lane = threadIdx.x & 63;
    if (lane == 0) { red[wave] = s; red[4 + wave] = s2; }
    __syncthreads();
    if (threadIdx.x == 0) {
        float ts  = red[0] + red[1] + red[2] + red[3];
        float ts2 = red[4] + red[5] + red[6] + red[7];
        float mu  = ts / NH;
        float var = ts2 / NH - mu * mu;
        red[0] = mu;
        red[1] = rsqrtf(var + 1e-5f);
    }
    __syncthreads();
    float mu = red[0], rstd = red[1];
    out[(size_t)tok * NH + h] = ((y - mu) * rstd) * gamma[h] + beta[h];
}

// ---------------------------------------------------------------------------
extern "C" void kernel_launch(void* const* d_in, const int* in_sizes, int n_in,
                              void* d_out, int out_size, void* d_ws, size_t ws_size,
                              hipStream_t stream) {
    const float* x      = (const float*)d_in[0];
    const float* gate_w = (const float*)d_in[1];
    const float* gate_b = (const float*)d_in[2];
    const float* w1     = (const float*)d_in[3];
    const float* b1     = (const float*)d_in[4];
    const float* w2     = (const float*)d_in[5];
    const float* b2     = (const float*)d_in[6];
    const float* gamma  = (const float*)d_in[7];
    const float* beta   = (const float*)d_in[8];
    float* out = (float*)d_out;

    char* ws = (char*)d_ws;
    const size_t MB = 1024 * 1024;
    int*    counts     = (int*)ws;                       // 256 B
    int*    bucket_enc = (int*)(ws + 256);               // 2 MB
    float*  bucket_gw  = (float*)(ws + 256 + 2 * MB);    // 2 MB
    bf16_t* w1t        = (bf16_t*)(ws + 256 + 4 * MB);   // 4 MB
    bf16_t* w2t        = (bf16_t*)(ws + 256 + 8 * MB);   // 4 MB
    bf16_t* xb         = (bf16_t*)(ws + 256 + 12 * MB);  // 16 MB
    bf16_t* pairbuf    = (bf16_t*)(ws + 256 + 28 * MB);  // 32 MB

    hipMemsetAsync(counts, 0, 256, stream);
    transpose_kernel<<<4096, 256, 0, stream>>>(w1, w2, w1t, w2t);
    gate_kernel<<<64, 256, 0, stream>>>(x, gate_w, gate_b, counts, bucket_enc, bucket_gw, xb);
    moe_kernel<<<1024, 256, 0, stream>>>(xb, w1t, b1, w2t, b2, counts, bucket_enc, bucket_gw, pairbuf);
    ln_kernel<<<NTOK, 256, 0, stream>>>(x, pairbuf, gamma, beta, out);
}